// Round 6
// baseline (748.076 us; speedup 1.0000x reference)
//
#include <hip/hip_runtime.h>
#include <stdint.h>
#include <stddef.h>

#define B_ 32
#define T_ 2048
#define F_ 1024
#define H_ 16
#define D_ 64
#define C_ 10

typedef __bf16 bf16;
typedef __bf16 bf16x8 __attribute__((ext_vector_type(8)));
typedef float f32x4 __attribute__((ext_vector_type(4)));

#define GLD_LDS16(g, l)                                                        \
  __builtin_amdgcn_global_load_lds(                                            \
      (const __attribute__((address_space(1))) void*)(g),                      \
      (__attribute__((address_space(3))) void*)(l), 16, 0, 0)

__device__ __forceinline__ float tanh_fast(float x) {
  float e = __expf(2.f * x);
  return 1.f - 2.f / (e + 1.f);
}

// ---------------------------------------------------------------- f32 -> bf16
__global__ __launch_bounds__(256) void k_cvt_bf16(const float* __restrict__ src,
                                                  bf16* __restrict__ dst, int n) {
  int i = (blockIdx.x * 256 + threadIdx.x) * 8;
  if (i + 8 <= n) {
    float4 a = *reinterpret_cast<const float4*>(src + i);
    float4 b = *reinterpret_cast<const float4*>(src + i + 4);
    bf16x8 o;
    o[0] = (bf16)a.x; o[1] = (bf16)a.y; o[2] = (bf16)a.z; o[3] = (bf16)a.w;
    o[4] = (bf16)b.x; o[5] = (bf16)b.y; o[6] = (bf16)b.z; o[7] = (bf16)b.w;
    *reinterpret_cast<bf16x8*>(dst + i) = o;
  }
}

// ------------------------------------------- fold conv_w/Wu/conv_b: W2T, B2
// W2T[h][k][d] = sum_c Wu[d,c]*conv_w[c,h,k];  B2[d] = sum_c Wu[d,c]*conv_b[c]
__global__ __launch_bounds__(256) void k_prep(const float* __restrict__ Wu,
                                              const float* __restrict__ cw,
                                              const float* __restrict__ cb,
                                              float* __restrict__ W2T,
                                              float* __restrict__ B2) {
  int tid = threadIdx.x;
  for (int idx = tid; idx < H_ * 3 * D_; idx += 256) {
    int d = idx & 63;
    int hk = idx >> 6;        // h*3 + k
    int h = hk / 3, k = hk % 3;
    float s = 0.f;
    for (int c = 0; c < C_; c++) s += Wu[d * C_ + c] * cw[c * H_ * 3 + h * 3 + k];
    W2T[idx] = s;
  }
  if (tid < D_) {
    float s = 0.f;
    for (int c = 0; c < C_; c++) s += Wu[tid * C_ + c] * cb[c];
    B2[tid] = s;
  }
}

// ---------------------------------------------------- q[b,e] + bias[e%64]
__global__ __launch_bounds__(256) void k_q(const float* __restrict__ query,
                                           const float* __restrict__ Wq,
                                           const float* __restrict__ bias,
                                           float* __restrict__ qv) {
  int gw = blockIdx.x * 4 + (threadIdx.x >> 6);
  int lane = threadIdx.x & 63;
  int b = gw >> 10, e = gw & 1023;
  const float* qr = query + (size_t)b * F_;
  const float* wr = Wq + (size_t)e * F_;
  float s = 0.f;
  for (int i = lane; i < F_; i += 64) s += qr[i] * wr[i];
  for (int off = 32; off; off >>= 1) s += __shfl_xor(s, off);
  if (lane == 0) qv[(size_t)b * F_ + e] = s + bias[e & 63];
}

// -------------------------------- loc[b,t,d] = tanh(conv-linear stencil)
__global__ __launch_bounds__(256) void k_loc(const float* __restrict__ pa,
                                             const float* __restrict__ W2T,
                                             const float* __restrict__ B2,
                                             float* __restrict__ loc) {
  int blk = blockIdx.x;              // B_ * T_/4 blocks
  int b = blk >> 9;
  int t0 = (blk & 511) * 4;
  __shared__ float sW[H_ * 3 * D_];  // 12 KB
  __shared__ float spa[H_][8];
  __shared__ float sB2[D_];
  int tid = threadIdx.x;
  for (int i = tid; i < H_ * 3 * D_; i += 256) sW[i] = W2T[i];
  if (tid < 96) {
    int h = tid / 6, j = tid % 6;
    int t = t0 - 1 + j;
    spa[h][j] = (t >= 0 && t < T_) ? pa[((size_t)b * H_ + h) * T_ + t] : 0.f;
  }
  if (tid < D_) sB2[tid] = B2[tid];
  __syncthreads();
  int tl = tid >> 6, d = tid & 63;
  float s = sB2[d];
#pragma unroll
  for (int h = 0; h < H_; h++)
#pragma unroll
    for (int k = 0; k < 3; k++)
      s += spa[h][tl + k] * sW[(h * 3 + k) * 64 + d];
  loc[((size_t)b * T_ + t0 + tl) * 64 + d] = tanh_fast(s);
}

// ------------------------------------------------------- main score GEMM
// score[b,h,t] = sum_d tanh( (value@Wv^T)[t, h*64+d] + qv[b,h*64+d] + loc[b,t,d] ) * sw[d]
__global__ __launch_bounds__(256, 4) void k_score(const bf16* __restrict__ vbf,
                                                  const bf16* __restrict__ wbf,
                                                  const float* __restrict__ qv,
                                                  const float* __restrict__ loc,
                                                  const float* __restrict__ sw,
                                                  float* __restrict__ score) {
  // 8192 blocks = 512 mtiles * 16 heads; XCD-chunked swizzle (8192 % 8 == 0)
  int wg = blockIdx.x;
  int swz = (wg & 7) * 1024 + (wg >> 3);
  int mtile = swz >> 4, h = swz & 15;
  int bb = mtile >> 4;             // 16 mtiles of 128 rows per sequence
  int t0 = (mtile & 15) << 7;

  __shared__ __align__(16) bf16 As[128 * 64];  // 16 KB, row stride 128 B
  __shared__ __align__(16) bf16 Bs[64 * 64];   //  8 KB

  int tid = threadIdx.x;
  int w = tid >> 6, l = tid & 63;
  const bf16* Ag = vbf + ((size_t)bb * T_ + t0) * F_;
  const bf16* Bg = wbf + ((size_t)h * 64) * F_;
  // inverse-swizzled source k-offset so linear global_load_lds dest + swizzled
  // ds_read agree (involution: 16B-slot ^= (row&7))
  int kswz = 8 * ((l & 7) ^ (l >> 3));
  int rsub = l >> 3;  // row-within-chunk

  f32x4 acc[2][4] = {};

  for (int kt = 0; kt < 16; kt++) {
    int kbase = kt * 64;
#pragma unroll
    for (int j = 0; j < 4; j++) {   // A chunks: 8 rows x 64 k each
      int c = w * 4 + j;
      const bf16* g = Ag + ((size_t)(c * 8 + rsub)) * F_ + kbase + kswz;
      GLD_LDS16(g, As + c * 512);
    }
#pragma unroll
    for (int j = 0; j < 2; j++) {   // B chunks
      int c = w * 2 + j;
      const bf16* g = Bg + ((size_t)(c * 8 + rsub)) * F_ + kbase + kswz;
      GLD_LDS16(g, Bs + c * 512);
    }
    __syncthreads();                // drains vmcnt+lgkmcnt

    int r = l & 15, g4 = l >> 4;
#pragma unroll
    for (int kk = 0; kk < 2; kk++) {
      bf16x8 a[2], bb_[4];
#pragma unroll
      for (int rt = 0; rt < 2; rt++) {
        int row = w * 32 + rt * 16 + r;
        int byte = row * 128 + (((kk * 4 + g4) ^ (row & 7)) << 4);
        a[rt] = *(const bf16x8*)((const char*)As + byte);
      }
#pragma unroll
      for (int ct = 0; ct < 4; ct++) {
        int e = ct * 16 + r;
        int byte = e * 128 + (((kk * 4 + g4) ^ (e & 7)) << 4);
        bb_[ct] = *(const bf16x8*)((const char*)Bs + byte);
      }
#pragma unroll
      for (int rt = 0; rt < 2; rt++)
#pragma unroll
        for (int ct = 0; ct < 4; ct++)
          acc[rt][ct] = __builtin_amdgcn_mfma_f32_16x16x32_bf16(
              a[rt], bb_[ct], acc[rt][ct], 0, 0, 0);
    }
    __syncthreads();
  }

  // epilogue: e=tanh(v+q+loc+bias), reduce over d (cols) -> score
  int r = l & 15, g4 = l >> 4;
  float qq[4], swv[4];
#pragma unroll
  for (int ct = 0; ct < 4; ct++) {
    int d = ct * 16 + r;
    qq[ct] = qv[(size_t)bb * F_ + h * 64 + d];  // bias already folded in
    swv[ct] = sw[d];
  }
#pragma unroll
  for (int rt = 0; rt < 2; rt++) {
#pragma unroll
    for (int rr = 0; rr < 4; rr++) {
      int trow = t0 + w * 32 + rt * 16 + g4 * 4 + rr;
      const float* lrow = loc + ((size_t)bb * T_ + trow) * 64;
      float p = 0.f;
#pragma unroll
      for (int ct = 0; ct < 4; ct++) {
        float x = acc[rt][ct][rr] + qq[ct] + lrow[ct * 16 + r];
        p += tanh_fast(x) * swv[ct];
      }
      p += __shfl_xor(p, 1);
      p += __shfl_xor(p, 2);
      p += __shfl_xor(p, 4);
      p += __shfl_xor(p, 8);
      if (r == 0)
        score[((size_t)bb * H_ + h) * T_ + trow] = p;
    }
  }
}

// ------------------------------------------------------------- softmax over T
__global__ __launch_bounds__(256) void k_softmax(const float* __restrict__ score,
                                                 float* __restrict__ align) {
  int bh = blockIdx.x;
  const float* s = score + (size_t)bh * T_;
  float* a = align + (size_t)bh * T_;
  int tid = threadIdx.x;
  float v[8];
  float m = -1e30f;
#pragma unroll
  for (int j = 0; j < 8; j++) {
    v[j] = s[tid + j * 256];
    m = fmaxf(m, v[j]);
  }
  for (int off = 32; off; off >>= 1) m = fmaxf(m, __shfl_xor(m, off));
  __shared__ float red[4], red2[4];
  int w = tid >> 6, l = tid & 63;
  if (l == 0) red[w] = m;
  __syncthreads();
  m = fmaxf(fmaxf(red[0], red[1]), fmaxf(red[2], red[3]));
  float sum = 0.f;
#pragma unroll
  for (int j = 0; j < 8; j++) {
    v[j] = __expf(v[j] - m);
    sum += v[j];
  }
  for (int off = 32; off; off >>= 1) sum += __shfl_xor(sum, off);
  if (l == 0) red2[w] = sum;
  __syncthreads();
  sum = red2[0] + red2[1] + red2[2] + red2[3];
  float inv = 1.f / sum;
#pragma unroll
  for (int j = 0; j < 8; j++) a[tid + j * 256] = v[j] * inv;
}

// --------------------- u_part[tc,b,h,f] = sum_{t in chunk} align[b,h,t]*value[b,t,f]
__global__ __launch_bounds__(256) void k_upart(const float* __restrict__ value,
                                               const float* __restrict__ align,
                                               float* __restrict__ upart) {
  int blk = blockIdx.x;  // tc*128 + b*4 + fc
  int tc = blk >> 7, b = (blk >> 2) & 31, fc = blk & 3;
  int tid = threadIdx.x;
  int f = fc * 256 + tid;
  __shared__ float sal[256][17];
  for (int idx = tid; idx < 256 * 16; idx += 256) {
    int hh = idx >> 8, tl = idx & 255;
    sal[tl][hh] = align[((size_t)b * H_ + hh) * T_ + tc * 256 + tl];
  }
  __syncthreads();
  float u[16];
#pragma unroll
  for (int h = 0; h < 16; h++) u[h] = 0.f;
  const float* vp = value + ((size_t)b * T_ + tc * 256) * F_ + f;
#pragma unroll 4
  for (int tl = 0; tl < 256; tl++) {
    float x = vp[(size_t)tl * F_];
#pragma unroll
    for (int h = 0; h < 16; h++) u[h] = fmaf(sal[tl][h], x, u[h]);
  }
#pragma unroll
  for (int h = 0; h < 16; h++)
    upart[(((size_t)tc * B_ + b) * H_ + h) * F_ + f] = u[h];
}

// ----------------- context[b, h*64+d] = sum_f (sum_tc upart) * Wv[h*64+d, f]
__global__ __launch_bounds__(256) void k_context(const float* __restrict__ upart,
                                                 const float* __restrict__ Wv,
                                                 float* __restrict__ ctx) {
  int bh = blockIdx.x;
  int b = bh >> 4, h = bh & 15;
  int tid = threadIdx.x;
  __shared__ float su[1024];
  for (int j = 0; j < 4; j++) {
    int f = tid + j * 256;
    float s = 0.f;
    for (int tc = 0; tc < 8; tc++)
      s += upart[(((size_t)tc * B_ + b) * H_ + h) * F_ + f];
    su[f] = s;
  }
  __syncthreads();
  int d = tid >> 2, part = tid & 3;
  const float* wr = Wv + ((size_t)(h * 64 + d)) * F_ + part * 256;
  float s = 0.f;
  for (int i = 0; i < 256; i++) s += su[part * 256 + i] * wr[i];
  s += __shfl_xor(s, 1);
  s += __shfl_xor(s, 2);
  if (part == 0) ctx[(size_t)b * F_ + h * 64 + d] = s;
}

extern "C" void kernel_launch(void* const* d_in, const int* in_sizes, int n_in,
                              void* d_out, int out_size, void* d_ws, size_t ws_size,
                              hipStream_t stream) {
  const float* query      = (const float*)d_in[0];
  const float* value      = (const float*)d_in[1];
  const float* prev_align = (const float*)d_in[2];
  const float* Wq         = (const float*)d_in[3];
  const float* Wv         = (const float*)d_in[4];
  const float* conv_w     = (const float*)d_in[5];
  const float* conv_b     = (const float*)d_in[6];
  const float* Wu         = (const float*)d_in[7];
  const float* bias       = (const float*)d_in[8];
  const float* score_w    = (const float*)d_in[9];
  // d_in[10] = score_b: softmax shift-invariant, provably unused.

  char* ws = (char*)d_ws;
  bf16*  vbf   = (bf16*)(ws + 0);                  // 134,217,728 B (dead after k_score)
  bf16*  wbf   = (bf16*)(ws + 134217728);          //   2,097,152 B
  float* qv    = (float*)(ws + 136314880);         //     131,072 B
  float* loc   = (float*)(ws + 136445952);         //  16,777,216 B
  float* W2T   = (float*)(ws + 153223168);         //      12,288 B
  float* B2    = (float*)(ws + 153235456);         //         256 B
  float* score = (float*)(ws + 153235712);         //   4,194,304 B (end ~157.4 MB)
  float* upart = (float*)(ws + 0);                 //  16,777,216 B — ALIASES vbf (safe: vbf dead)

  float* ctx   = (float*)d_out;                    // (32,1,1024)
  float* align = (float*)d_out + 32768;            // (32,16,2048)

  k_cvt_bf16<<<32768, 256, 0, stream>>>(value, vbf, B_ * T_ * F_);
  k_cvt_bf16<<<512, 256, 0, stream>>>(Wv, wbf, F_ * F_);
  k_prep<<<1, 256, 0, stream>>>(Wu, conv_w, conv_b, W2T, B2);
  k_q<<<8192, 256, 0, stream>>>(query, Wq, bias, qv);
  k_loc<<<B_ * T_ / 4, 256, 0, stream>>>(prev_align, W2T, B2, loc);
  k_score<<<8192, 256, 0, stream>>>(vbf, wbf, qv, loc, score_w, score);
  k_softmax<<<B_ * H_, 256, 0, stream>>>(score, align);
  k_upart<<<1024, 256, 0, stream>>>(value, align, upart);
  k_context<<<B_ * H_, 256, 0, stream>>>(upart, Wv, ctx);
}

// Round 12
// 743.917 us; speedup vs baseline: 1.0056x; 1.0056x over previous
//
#include <hip/hip_runtime.h>
#include <stdint.h>
#include <stddef.h>

#define B_ 32
#define T_ 2048
#define F_ 1024
#define H_ 16
#define D_ 64
#define C_ 10

typedef __bf16 bf16;
typedef __bf16 bf16x8 __attribute__((ext_vector_type(8)));
typedef float f32x4 __attribute__((ext_vector_type(4)));

#define GLD_LDS16(g, l)                                                        \
  __builtin_amdgcn_global_load_lds(                                            \
      (const __attribute__((address_space(1))) void*)(g),                      \
      (__attribute__((address_space(3))) void*)(l), 16, 0, 0)

__device__ __forceinline__ float tanh_fast(float x) {
  float e = __expf(2.f * x);
  return 1.f - 2.f / (e + 1.f);
}

// ---------------------------------------------------------------- f32 -> bf16
__global__ __launch_bounds__(256) void k_cvt_bf16(const float* __restrict__ src,
                                                  bf16* __restrict__ dst, int n) {
  int i = (blockIdx.x * 256 + threadIdx.x) * 8;
  if (i + 8 <= n) {
    float4 a = *reinterpret_cast<const float4*>(src + i);
    float4 b = *reinterpret_cast<const float4*>(src + i + 4);
    bf16x8 o;
    o[0] = (bf16)a.x; o[1] = (bf16)a.y; o[2] = (bf16)a.z; o[3] = (bf16)a.w;
    o[4] = (bf16)b.x; o[5] = (bf16)b.y; o[6] = (bf16)b.z; o[7] = (bf16)b.w;
    *reinterpret_cast<bf16x8*>(dst + i) = o;
  }
}

// ------------------------------------------- fold conv_w/Wu/conv_b: W2T, B2
// W2T[h][k][d] = sum_c Wu[d,c]*conv_w[c,h,k];  B2[d] = sum_c Wu[d,c]*conv_b[c]
__global__ __launch_bounds__(256) void k_prep(const float* __restrict__ Wu,
                                              const float* __restrict__ cw,
                                              const float* __restrict__ cb,
                                              float* __restrict__ W2T,
                                              float* __restrict__ B2) {
  int tid = threadIdx.x;
  for (int idx = tid; idx < H_ * 3 * D_; idx += 256) {
    int d = idx & 63;
    int hk = idx >> 6;        // h*3 + k
    int h = hk / 3, k = hk % 3;
    float s = 0.f;
    for (int c = 0; c < C_; c++) s += Wu[d * C_ + c] * cw[c * H_ * 3 + h * 3 + k];
    W2T[idx] = s;
  }
  if (tid < D_) {
    float s = 0.f;
    for (int c = 0; c < C_; c++) s += Wu[tid * C_ + c] * cb[c];
    B2[tid] = s;
  }
}

// ------------------- qv[b,e] = dot(query[b], Wq[e]) + bias[e%64] (e-major,
// Wq row staged once in LDS instead of 32x re-read)
__global__ __launch_bounds__(256) void k_q(const float* __restrict__ query,
                                           const float* __restrict__ Wq,
                                           const float* __restrict__ bias,
                                           float* __restrict__ qv) {
  int e = blockIdx.x;                 // 1024 blocks
  __shared__ float swq[F_];
  int tid = threadIdx.x;
  const float* wr = Wq + (size_t)e * F_;
  for (int i = tid; i < F_; i += 256) swq[i] = wr[i];
  __syncthreads();
  int w = tid >> 6, l = tid & 63;     // wave w handles b = w*8 .. w*8+7
  float s[8];
#pragma unroll
  for (int j = 0; j < 8; j++) s[j] = 0.f;
  for (int i = l; i < F_; i += 64) {
    float wv = swq[i];
#pragma unroll
    for (int j = 0; j < 8; j++)
      s[j] += query[(size_t)(w * 8 + j) * F_ + i] * wv;
  }
#pragma unroll
  for (int j = 0; j < 8; j++)
    for (int off = 32; off; off >>= 1) s[j] += __shfl_xor(s[j], off);
  if (l == 0) {
    float bb = bias[e & 63];
#pragma unroll
    for (int j = 0; j < 8; j++) qv[(size_t)(w * 8 + j) * F_ + e] = s[j] + bb;
  }
}

// -------------------------------- loc[b,t,d] = tanh(conv-linear stencil)
__global__ __launch_bounds__(256) void k_loc(const float* __restrict__ pa,
                                             const float* __restrict__ W2T,
                                             const float* __restrict__ B2,
                                             float* __restrict__ loc) {
  int blk = blockIdx.x;              // B_ * T_/4 blocks
  int b = blk >> 9;
  int t0 = (blk & 511) * 4;
  __shared__ float sW[H_ * 3 * D_];  // 12 KB
  __shared__ float spa[H_][8];
  __shared__ float sB2[D_];
  int tid = threadIdx.x;
  for (int i = tid; i < H_ * 3 * D_; i += 256) sW[i] = W2T[i];
  if (tid < 96) {
    int h = tid / 6, j = tid % 6;
    int t = t0 - 1 + j;
    spa[h][j] = (t >= 0 && t < T_) ? pa[((size_t)b * H_ + h) * T_ + t] : 0.f;
  }
  if (tid < D_) sB2[tid] = B2[tid];
  __syncthreads();
  int tl = tid >> 6, d = tid & 63;
  float s = sB2[d];
#pragma unroll
  for (int h = 0; h < H_; h++)
#pragma unroll
    for (int k = 0; k < 3; k++)
      s += spa[h][tl + k] * sW[(h * 3 + k) * 64 + d];
  loc[((size_t)b * T_ + t0 + tl) * 64 + d] = tanh_fast(s);
}

// ------------------------------------------------------- main score GEMM
// 128x128 tile (2 heads per block), BK=64, m97-style 2-barrier loop.
// score[b,h,t] = sum_d tanh( (value@Wv^T)[t,h*64+d] + qv[b,h*64+d] + loc[b,t,d] ) * sw[d]
__global__ __launch_bounds__(256, 3) void k_score(const bf16* __restrict__ vbf,
                                                  const bf16* __restrict__ wbf,
                                                  const float* __restrict__ qv,
                                                  const float* __restrict__ loc,
                                                  const float* __restrict__ sw,
                                                  float* __restrict__ score) {
  // 4096 blocks = 512 mtiles * 8 head-pairs; XCD-chunked swizzle (4096%8==0)
  int wg = blockIdx.x;
  int swz = (wg & 7) * 512 + (wg >> 3);
  int mtile = swz >> 3, hp = swz & 7;   // hp = head-pair (cols hp*128..+127)
  int bb = mtile >> 4;                  // 16 mtiles of 128 rows per sequence
  int t0 = (mtile & 15) << 7;

  __shared__ __align__(16) bf16 As[128 * 64];  // 16 KB, row stride 128 B
  __shared__ __align__(16) bf16 Bs[128 * 64];  // 16 KB

  int tid = threadIdx.x;
  int w = tid >> 6, l = tid & 63;
  const bf16* Ag = vbf + ((size_t)bb * T_ + t0) * F_;
  const bf16* Bg = wbf + ((size_t)hp * 128) * F_;
  // inverse-swizzled source k-offset so linear global_load_lds dest + swizzled
  // ds_read agree (involution: 16B-slot ^= (row&7))
  int kswz = 8 * ((l & 7) ^ (l >> 3));
  int rsub = l >> 3;  // row-within-chunk

  f32x4 acc[2][8] = {};

  for (int kt = 0; kt < 16; kt++) {
    int kbase = kt * 64;
#pragma unroll
    for (int j = 0; j < 4; j++) {   // A chunks: 8 rows x 64 k each
      int c = w * 4 + j;
      GLD_LDS16(Ag + ((size_t)(c * 8 + rsub)) * F_ + kbase + kswz, As + c * 512);
    }
#pragma unroll
    for (int j = 0; j < 4; j++) {   // B chunks
      int c = w * 4 + j;
      GLD_LDS16(Bg + ((size_t)(c * 8 + rsub)) * F_ + kbase + kswz, Bs + c * 512);
    }
    __syncthreads();                // drains vmcnt+lgkmcnt

    int r = l & 15, g4 = l >> 4;
#pragma unroll
    for (int kk = 0; kk < 2; kk++) {
      bf16x8 a[2], bq[8];
#pragma unroll
      for (int rt = 0; rt < 2; rt++) {
        int row = w * 32 + rt * 16 + r;
        int byte = row * 128 + (((kk * 4 + g4) ^ (row & 7)) << 4);
        a[rt] = *(const bf16x8*)((const char*)As + byte);
      }
#pragma unroll
      for (int ct = 0; ct < 8; ct++) {
        int e = ct * 16 + r;
        int byte = e * 128 + (((kk * 4 + g4) ^ (e & 7)) << 4);
        bq[ct] = *(const bf16x8*)((const char*)Bs + byte);
      }
#pragma unroll
      for (int rt = 0; rt < 2; rt++)
#pragma unroll
        for (int ct = 0; ct < 8; ct++)
          acc[rt][ct] = __builtin_amdgcn_mfma_f32_16x16x32_bf16(
              a[rt], bq[ct], acc[rt][ct], 0, 0, 0);
    }
    __syncthreads();
  }

  // epilogue: e=tanh(v+q+loc), reduce over d within each 64-col head -> score
  int r = l & 15, g4 = l >> 4;
  float qq[8], swv[8];
#pragma unroll
  for (int ct = 0; ct < 8; ct++) {
    int el = ct * 16 + r;
    qq[ct] = qv[(size_t)bb * F_ + hp * 128 + el];  // bias already folded in
    swv[ct] = sw[el & 63];
  }
#pragma unroll
  for (int rt = 0; rt < 2; rt++) {
#pragma unroll
    for (int rr = 0; rr < 4; rr++) {
      int trow = t0 + w * 32 + rt * 16 + g4 * 4 + rr;
      const float* lrow = loc + ((size_t)bb * T_ + trow) * 64;
      float lv[4];
#pragma unroll
      for (int j = 0; j < 4; j++) lv[j] = lrow[j * 16 + r];
      float p0 = 0.f, p1 = 0.f;
#pragma unroll
      for (int ct = 0; ct < 4; ct++) {
        p0 += tanh_fast(acc[rt][ct][rr] + qq[ct] + lv[ct]) * swv[ct];
        p1 += tanh_fast(acc[rt][ct + 4][rr] + qq[ct + 4] + lv[ct]) * swv[ct + 4];
      }
      p0 += __shfl_xor(p0, 1); p1 += __shfl_xor(p1, 1);
      p0 += __shfl_xor(p0, 2); p1 += __shfl_xor(p1, 2);
      p0 += __shfl_xor(p0, 4); p1 += __shfl_xor(p1, 4);
      p0 += __shfl_xor(p0, 8); p1 += __shfl_xor(p1, 8);
      if (r == 0) {
        score[((size_t)bb * H_ + hp * 2) * T_ + trow] = p0;
        score[((size_t)bb * H_ + hp * 2 + 1) * T_ + trow] = p1;
      }
    }
  }
}

// ------------------------------------------------------------- softmax over T
__global__ __launch_bounds__(256) void k_softmax(const float* __restrict__ score,
                                                 float* __restrict__ align) {
  int bh = blockIdx.x;
  const float* s = score + (size_t)bh * T_;
  float* a = align + (size_t)bh * T_;
  int tid = threadIdx.x;
  float v[8];
  float m = -1e30f;
#pragma unroll
  for (int j = 0; j < 8; j++) {
    v[j] = s[tid + j * 256];
    m = fmaxf(m, v[j]);
  }
  for (int off = 32; off; off >>= 1) m = fmaxf(m, __shfl_xor(m, off));
  __shared__ float red[4], red2[4];
  int w = tid >> 6, l = tid & 63;
  if (l == 0) red[w] = m;
  __syncthreads();
  m = fmaxf(fmaxf(red[0], red[1]), fmaxf(red[2], red[3]));
  float sum = 0.f;
#pragma unroll
  for (int j = 0; j < 8; j++) {
    v[j] = __expf(v[j] - m);
    sum += v[j];
  }
  for (int off = 32; off; off >>= 1) sum += __shfl_xor(sum, off);
  if (l == 0) red2[w] = sum;
  __syncthreads();
  sum = red2[0] + red2[1] + red2[2] + red2[3];
  float inv = 1.f / sum;
#pragma unroll
  for (int j = 0; j < 8; j++) a[tid + j * 256] = v[j] * inv;
}

// --------------------- u_part[tc,b,h,f] = sum_{t in chunk} align[b,h,t]*value[b,t,f]
__global__ __launch_bounds__(256) void k_upart(const float* __restrict__ value,
                                               const float* __restrict__ align,
                                               float* __restrict__ upart) {
  int blk = blockIdx.x;  // tc*64 + b*2 + fc   (512 blocks)
  int tc = blk >> 6, b = (blk >> 1) & 31, fc = blk & 1;
  int tid = threadIdx.x;
  int f = fc * 512 + tid * 2;
  __shared__ float sal[256][17];
  for (int idx = tid; idx < 256 * 16; idx += 256) {
    int hh = idx >> 8, tl = idx & 255;
    sal[tl][hh] = align[((size_t)b * H_ + hh) * T_ + tc * 256 + tl];
  }
  __syncthreads();
  float ux[16], uy[16];
#pragma unroll
  for (int h = 0; h < 16; h++) { ux[h] = 0.f; uy[h] = 0.f; }
  const float* vp = value + ((size_t)b * T_ + tc * 256) * F_ + f;
#pragma unroll 4
  for (int tl = 0; tl < 256; tl++) {
    float2 x = *reinterpret_cast<const float2*>(vp + (size_t)tl * F_);
#pragma unroll
    for (int h = 0; h < 16; h++) {
      float al = sal[tl][h];
      ux[h] = fmaf(al, x.x, ux[h]);
      uy[h] = fmaf(al, x.y, uy[h]);
    }
  }
#pragma unroll
  for (int h = 0; h < 16; h++) {
    float2 o; o.x = ux[h]; o.y = uy[h];
    *reinterpret_cast<float2*>(
        &upart[(((size_t)tc * B_ + b) * H_ + h) * F_ + f]) = o;
  }
}

// ----------------- context[b, h*64+d] = sum_f (sum_tc upart) * Wv[h*64+d, f]
__global__ __launch_bounds__(256) void k_context(const float* __restrict__ upart,
                                                 const float* __restrict__ Wv,
                                                 float* __restrict__ ctx) {
  int bh = blockIdx.x;
  int b = bh >> 4, h = bh & 15;
  int tid = threadIdx.x;
  __shared__ float su[1024];
  for (int j = 0; j < 4; j++) {
    int f = tid + j * 256;
    float s = 0.f;
    for (int tc = 0; tc < 8; tc++)
      s += upart[(((size_t)tc * B_ + b) * H_ + h) * F_ + f];
    su[f] = s;
  }
  __syncthreads();
  int d = tid >> 2, part = tid & 3;
  const float* wr = Wv + ((size_t)(h * 64 + d)) * F_ + part * 256;
  float s = 0.f;
  for (int i = 0; i < 256; i++) s += su[part * 256 + i] * wr[i];
  s += __shfl_xor(s, 1);
  s += __shfl_xor(s, 2);
  if (part == 0) ctx[(size_t)b * F_ + h * 64 + d] = s;
}

extern "C" void kernel_launch(void* const* d_in, const int* in_sizes, int n_in,
                              void* d_out, int out_size, void* d_ws, size_t ws_size,
                              hipStream_t stream) {
  const float* query      = (const float*)d_in[0];
  const float* value      = (const float*)d_in[1];
  const float* prev_align = (const float*)d_in[2];
  const float* Wq         = (const float*)d_in[3];
  const float* Wv         = (const float*)d_in[4];
  const float* conv_w     = (const float*)d_in[5];
  const float* conv_b     = (const float*)d_in[6];
  const float* Wu         = (const float*)d_in[7];
  const float* bias       = (const float*)d_in[8];
  const float* score_w    = (const float*)d_in[9];
  // d_in[10] = score_b: softmax shift-invariant, provably unused.

  char* ws = (char*)d_ws;
  bf16*  vbf   = (bf16*)(ws + 0);                  // 134,217,728 B (dead after k_score)
  bf16*  wbf   = (bf16*)(ws + 134217728);          //   2,097,152 B
  float* qv    = (float*)(ws + 136314880);         //     131,072 B
  float* loc   = (float*)(ws + 136445952);         //  16,777,216 B
  float* W2T   = (float*)(ws + 153223168);         //      12,288 B
  float* B2    = (float*)(ws + 153235456);         //         256 B
  float* score = (float*)(ws + 153235712);         //   4,194,304 B (end ~157.4 MB)
  float* upart = (float*)(ws + 0);                 //  16,777,216 B — ALIASES vbf (safe: vbf dead)

  float* ctx   = (float*)d_out;                    // (32,1,1024)
  float* align = (float*)d_out + 32768;            // (32,16,2048)

  k_cvt_bf16<<<32768, 256, 0, stream>>>(value, vbf, B_ * T_ * F_);
  k_cvt_bf16<<<512, 256, 0, stream>>>(Wv, wbf, F_ * F_);
  k_prep<<<1, 256, 0, stream>>>(Wu, conv_w, conv_b, W2T, B2);
  k_q<<<1024, 256, 0, stream>>>(query, Wq, bias, qv);
  k_loc<<<B_ * T_ / 4, 256, 0, stream>>>(prev_align, W2T, B2, loc);
  k_score<<<4096, 256, 0, stream>>>(vbf, wbf, qv, loc, score_w, score);
  k_softmax<<<B_ * H_, 256, 0, stream>>>(score, align);
  k_upart<<<512, 256, 0, stream>>>(value, align, upart);
  k_context<<<B_ * H_, 256, 0, stream>>>(upart, Wv, ctx);
}